// Round 3
// baseline (436.289 us; speedup 1.0000x reference)
//
#include <hip/hip_runtime.h>
#include <hip/hip_bf16.h>

// KGE graph encoder, pruned to the backward cone of the 64 CLS nodes.
// R3: atomic-free hot path. Scans write to per-block private segments
// (no global counter atomics); 1-block prefix + compact merges them.
// Pruned edge lists are CSR'd by destination, then each layer is one
// block-per-dst kernel doing softmax + aggregation + (layer1) projection
// with no atomics. k_rel fused into k_feat0 launch.

#define NN   50000      // N_NODES
#define NE   800000     // N_EDGES
#define NR   500        // N_REL
#define HH   8          // heads
#define DD   16         // per-head dim
#define HIDD 128        // HID == IN
#define BB   64         // batch (CLS nodes)

#define GRIDS 1024      // scan grid
#define PER   784       // edges per scan block (GRIDS*PER >= NE, PER%4==0)

#define MAXE2 16384     // cap on |{e : dst in S2}|   (expect ~1K)
#define MAXS1 16448     // cap on |S1|                (expect ~1.1K)
#define MAXE1 262144    // cap on |{e : dst in S1}|   (expect ~18K)
#define MAXS0 50000     // node set, can't exceed NN  (expect ~19K)

// counters: [0]=cntS1 [1]=cntS0 [2]=cntE2 [3]=cntE1

__global__ void k_init(int* slot2, int* slot1, int* slot0, int* counters) {
    int i = blockIdx.x * blockDim.x + threadIdx.x;
    int stride = gridDim.x * blockDim.x;
    for (int n = i; n < NN; n += stride) { slot2[n] = -1; slot1[n] = -1; slot0[n] = -1; }
    if (i < 8) counters[i] = 0;
}

__global__ void k_seed(const int* goffs, int* slot2, int* slot1, int* nodesS1) {
    int i = threadIdx.x;
    if (i < BB) {
        int n = goffs[i];
        slot2[n] = i;        // graph index
        slot1[n] = -2;       // claimed member of S1; slot assigned in k_prefix2
        nodesS1[i] = n;
    }
}

// Frontier scan: edges with slotHit[dst]>=0 go to this block's private
// segment; their srcs are CAS-claimed in slotNew and appended to the node
// segment. No global atomics at all.
__global__ void k_scan(const int* __restrict__ src, const int* __restrict__ dst,
                       const int* __restrict__ slotHit, int* __restrict__ slotNew,
                       int* eseg, int* ecnt, int* nseg, int* ncnt) {
    __shared__ int cE, cN;
    if (threadIdx.x == 0) { cE = 0; cN = 0; }
    __syncthreads();
    int b = blockIdx.x;
    int lo = b * PER;
    int hi = lo + PER; if (hi > NE) hi = NE;
    int* es = eseg + (size_t)b * PER;
    int* ns = nseg + (size_t)b * PER;
    for (int e = lo + threadIdx.x; e < hi; e += blockDim.x) {
        int d = dst[e];
        if (slotHit[d] >= 0) {
            int pos = atomicAdd(&cE, 1);          // LDS atomic
            es[pos] = e;                          // pos < edges-in-range <= PER
            int s = src[e];
            if (atomicCAS(&slotNew[s], -1, -2) == -1) {
                int p = atomicAdd(&cN, 1);
                ns[p] = s;
            }
        }
    }
    __syncthreads();
    if (threadIdx.x == 0) { ecnt[b] = cE; ncnt[b] = cN; }
}

// exclusive scan over nblk<=GRIDS counts, 256 threads; returns total
__device__ int block_scan_counts(const int* cnts, int nblk, int* bases, int offset) {
    __shared__ int part[256];
    __shared__ int total_sh;
    int t = threadIdx.x;
    int per = (nblk + 255) / 256;
    int s = 0;
    for (int j = 0; j < per; j++) { int i = t * per + j; if (i < nblk) s += cnts[i]; }
    part[t] = s;
    __syncthreads();
    for (int d = 1; d < 256; d <<= 1) {
        int v = (t >= d) ? part[t - d] : 0;
        __syncthreads();
        part[t] += v;
        __syncthreads();
    }
    int run = ((t == 0) ? 0 : part[t - 1]) + offset;
    for (int j = 0; j < per; j++) {
        int i = t * per + j;
        if (i < nblk) { bases[i] = run; run += cnts[i]; }
    }
    if (t == 255) total_sh = part[255];
    __syncthreads();
    return total_sh;
}

__global__ void k_prefix2(const int* ecnt2, const int* ncnt2, int* ebase2, int* nbase2,
                          int* counters, const int* nodesS1, int* slot1, int* slot0,
                          int* nodesS0) {
    int t = threadIdx.x;
    int totE = block_scan_counts(ecnt2, GRIDS, ebase2, 0);
    int totN = block_scan_counts(ncnt2, GRIDS, nbase2, BB);
    if (t == 0) {
        counters[2] = totE;
        counters[0] = BB + totN;
        counters[1] = BB + totN;
    }
    if (t < BB) {   // CLS nodes occupy slots 0..63 of S1 (and S0)
        int n = nodesS1[t];
        slot1[n] = t;
        slot0[n] = t;
        nodesS0[t] = n;
    }
}

__global__ void k_compact2(const int* eseg2, const int* ecnt2, const int* ebase2,
                           const int* nseg2, const int* ncnt2, const int* nbase2,
                           int* e2list, int* nodesS1, int* slot1, int* slot0,
                           int* nodesS0, int* deg2) {
    int b = blockIdx.x, t = threadIdx.x;
    int ce = ecnt2[b], cn = ncnt2[b], be = ebase2[b], bn = nbase2[b];
    const int* es = eseg2 + (size_t)b * PER;
    const int* ns = nseg2 + (size_t)b * PER;
    for (int i = t; i < ce; i += blockDim.x) {
        int g = be + i; if (g < MAXE2) e2list[g] = es[i];
    }
    for (int i = t; i < cn; i += blockDim.x) {
        int idx = bn + i;
        if (idx < MAXS1) {
            int n = ns[i];
            nodesS1[idx] = n;
            slot1[n] = idx;
            slot0[n] = idx;
            nodesS0[idx] = n;
        }
    }
    if (b == 0) { for (int i = t; i < BB; i += blockDim.x) deg2[i] = 0; }
}

__global__ void k_prefix1(const int* ecnt1, const int* ncnt1, int* ebase1, int* nbase1,
                          int* counters) {
    int t = threadIdx.x;
    int s0 = counters[1];                     // uniform read
    int totE = block_scan_counts(ecnt1, GRIDS, ebase1, 0);
    int totN = block_scan_counts(ncnt1, GRIDS, nbase1, s0);
    if (t == 0) {
        counters[3] = totE;
        counters[1] = s0 + totN;
    }
}

__global__ void k_compact1(const int* eseg1, const int* ecnt1, const int* ebase1,
                           const int* nseg1, const int* ncnt1, const int* nbase1,
                           int* e1list, int* slot0, int* nodesS0,
                           int* deg1, const int* counters) {
    int b = blockIdx.x, t = threadIdx.x;
    int ce = ecnt1[b], cn = ncnt1[b], be = ebase1[b], bn = nbase1[b];
    const int* es = eseg1 + (size_t)b * PER;
    const int* ns = nseg1 + (size_t)b * PER;
    for (int i = t; i < ce; i += blockDim.x) {
        int g = be + i; if (g < MAXE1) e1list[g] = es[i];
    }
    for (int i = t; i < cn; i += blockDim.x) {
        int idx = bn + i;
        if (idx < MAXS0) {
            int n = ns[i];
            slot0[n] = idx;
            nodesS0[idx] = n;
        }
    }
    int cnt1 = counters[0]; if (cnt1 > MAXS1) cnt1 = MAXS1;
    for (int i = b * blockDim.x + t; i < cnt1; i += gridDim.x * blockDim.x) deg1[i] = 0;
}

__global__ void k_hist(const int* e2list, const int* e1list, const int* counters,
                       const int* dst, const int* slot2, const int* slot1,
                       int* deg2, int* deg1) {
    int i = blockIdx.x * blockDim.x + threadIdx.x;
    int stride = gridDim.x * blockDim.x;
    int c2 = counters[2]; if (c2 > MAXE2) c2 = MAXE2;
    int c1 = counters[3]; if (c1 > MAXE1) c1 = MAXE1;
    for (int k = i; k < c2; k += stride) atomicAdd(&deg2[slot2[dst[e2list[k]]]], 1);
    for (int k = i; k < c1; k += stride) atomicAdd(&deg1[slot1[dst[e1list[k]]]], 1);
}

__device__ void excl_scan_glob(const int* deg, int n, int* rp) {
    __shared__ int part[256];
    int t = threadIdx.x;
    int per = (n + 255) / 256;
    int s = 0;
    for (int j = 0; j < per; j++) { int i = t * per + j; if (i < n) s += deg[i]; }
    part[t] = s;
    __syncthreads();
    for (int d = 1; d < 256; d <<= 1) {
        int v = (t >= d) ? part[t - d] : 0;
        __syncthreads();
        part[t] += v;
        __syncthreads();
    }
    int run = (t == 0) ? 0 : part[t - 1];
    for (int j = 0; j < per; j++) {
        int i = t * per + j;
        if (i < n) { rp[i] = run; run += deg[i]; }
    }
    if (t == 255) rp[n] = part[255];
    __syncthreads();
}

__global__ void k_rowptr(const int* deg2, const int* deg1, const int* counters,
                         int* rp2, int* rp1, int* cur2, int* cur1) {
    int t = threadIdx.x;
    int cnt1 = counters[0]; if (cnt1 > MAXS1) cnt1 = MAXS1;
    excl_scan_glob(deg2, BB, rp2);
    excl_scan_glob(deg1, cnt1, rp1);
    for (int i = t; i < BB; i += blockDim.x) cur2[i] = rp2[i];
    for (int i = t; i < cnt1; i += blockDim.x) cur1[i] = rp1[i];
}

__global__ void k_scatter(const int* e2list, const int* e1list, const int* counters,
                          const int* dst, const int* slot2, const int* slot1,
                          int* cur2, int* cur1, int* csr2, int* csr1) {
    int i = blockIdx.x * blockDim.x + threadIdx.x;
    int stride = gridDim.x * blockDim.x;
    int c2 = counters[2]; if (c2 > MAXE2) c2 = MAXE2;
    int c1 = counters[3]; if (c1 > MAXE1) c1 = MAXE1;
    for (int k = i; k < c2; k += stride) {
        int e = e2list[k];
        int pos = atomicAdd(&cur2[slot2[dst[e]]], 1);
        if (pos < MAXE2) csr2[pos] = e;
    }
    for (int k = i; k < c1; k += stride) {
        int e = e1list[k];
        int pos = atomicAdd(&cur1[slot1[dst[e]]], 1);
        if (pos < MAXE1) csr1[pos] = e;
    }
}

// Fused: blocks [0, 2*NR) project rel_table (rproj, ee); remaining blocks
// compute feat0/el0/er0 for S0 nodes, 8 nodes per tile (W_ent amortized).
#define FT 8
__global__ void k_relfeat0(const float* rel_table, const float* __restrict__ W_rel,
                           const float* attn_e, float* rproj, float* ee,
                           const int* nodesS0, const int* counters, const int* ent_ids,
                           const float* __restrict__ ent_table,
                           const float* __restrict__ W_ent,
                           const float* __restrict__ attn_l,
                           const float* __restrict__ attn_r,
                           float* feat0, float* el0, float* er0) {
    __shared__ float rows[FT][HIDD];
    int t = threadIdx.x;              // 0..127
    if (blockIdx.x < 2 * NR) {
        int l = blockIdx.x / NR, r = blockIdx.x % NR;
        rows[0][t] = rel_table[r * HIDD + t];
        __syncthreads();
        const float* W = W_rel + l * HIDD * HIDD;
        float acc = 0.f;
        for (int j = 0; j < HIDD; j++) acc += rows[0][j] * W[j * HIDD + t];
        rproj[(l * NR + r) * HIDD + t] = acc;
        rows[1][t] = acc;
        __syncthreads();
        if (t < HH) {
            float s = 0.f;
            for (int d = 0; d < DD; d++)
                s += rows[1][t * DD + d] * attn_e[(l * HH + t) * DD + d];
            ee[(l * NR + r) * HH + t] = s;
        }
        return;
    }
    int cnt = counters[1]; if (cnt > MAXS0) cnt = MAXS0;
    int tile0 = blockIdx.x - 2 * NR;
    int tstride = gridDim.x - 2 * NR;
    int nTiles = (cnt + FT - 1) / FT;
    for (int tile = tile0; tile < nTiles; tile += tstride) {
        int k0 = tile * FT;
        #pragma unroll
        for (int m = 0; m < FT; m++) {
            int k = k0 + m;
            int n = nodesS0[k < cnt ? k : 0];
            rows[m][t] = ent_table[(long)ent_ids[n] * HIDD + t];
        }
        __syncthreads();
        float acc[FT];
        #pragma unroll
        for (int m = 0; m < FT; m++) acc[m] = 0.f;
        for (int j = 0; j < HIDD; j++) {
            float w = W_ent[j * HIDD + t];
            #pragma unroll
            for (int m = 0; m < FT; m++) acc[m] += rows[m][j] * w;
        }
        __syncthreads();
        #pragma unroll
        for (int m = 0; m < FT; m++) {
            int k = k0 + m;
            if (k < cnt) feat0[k * HIDD + t] = acc[m];
            rows[m][t] = acc[m];
        }
        __syncthreads();
        {   // 8 nodes x 8 heads x {el,er} = 128 tasks
            int m = t >> 4, idx = t & 15, h = idx >> 1, isR = idx & 1;
            int k = k0 + m;
            if (k < cnt) {
                const float* av = (isR ? attn_r : attn_l) + h * DD;
                float s = 0.f;
                for (int d = 0; d < DD; d++) s += rows[m][h * DD + d] * av[d];
                if (isR) er0[k * HH + h] = s; else el0[k * HH + h] = s;
            }
        }
        __syncthreads();
    }
}

// Layer 1: one block per S1 node. Softmax + aggregation + W_ent[1]
// projection + el1/er1, no atomics.
__global__ void k_layer1(const int* counters, const int* rp1, const int* csr1,
                         const int* src, const int* rel_ids, const int* slot0,
                         const float* __restrict__ el0, const float* __restrict__ er0,
                         const float* __restrict__ ee0,
                         const float* __restrict__ feat0, const float* __restrict__ rproj0,
                         const float* __restrict__ W_ent1,
                         const float* attn_l1, const float* attn_r1,
                         float* feat1, float* el1, float* er1) {
    int cnt1 = counters[0]; if (cnt1 > MAXS1) cnt1 = MAXS1;
    int t = threadIdx.x;              // 0..127
    int h = t >> 4;
    __shared__ float row[HIDD];
    __shared__ float f2[HIDD];
    for (int k = blockIdx.x; k < cnt1; k += gridDim.x) {
        int lo = rp1[k], hi = rp1[k + 1];
        float er_k = er0[k * HH + h];     // slot0 of an S1 node == its slot1
        float acc = 0.f, sumex = 0.f;
        for (int i = lo; i < hi; i++) {
            int e = csr1[i];
            int ks = slot0[src[e]];
            int rid = rel_ids[e];
            float sc = el0[ks * HH + h] + er_k + ee0[rid * HH + h];
            sc = sc >= 0.f ? sc : 0.2f * sc;
            float ex = __expf(sc);
            sumex += ex;
            acc += ex * (feat0[ks * HIDD + t] + rproj0[rid * HIDD + t]);
        }
        row[t] = (hi > lo) ? acc / sumex : 0.f;
        __syncthreads();
        float f = 0.f;
        for (int j = 0; j < HIDD; j++) f += row[j] * W_ent1[j * HIDD + t];
        feat1[k * HIDD + t] = f;
        f2[t] = f;
        __syncthreads();
        if (t < HH) {
            float s = 0.f;
            for (int d = 0; d < DD; d++) s += f2[t * DD + d] * attn_l1[t * DD + d];
            el1[k * HH + t] = s;
        } else if (t < 2 * HH) {
            int hh = t - HH;
            float s = 0.f;
            for (int d = 0; d < DD; d++) s += f2[hh * DD + d] * attn_r1[hh * DD + d];
            er1[k * HH + hh] = s;
        }
        __syncthreads();
    }
}

// Layer 2: one block per CLS node (graph), writes output directly.
__global__ void k_layer2(const int* rp2, const int* csr2,
                         const int* src, const int* rel_ids, const int* slot1,
                         const float* __restrict__ el1, const float* __restrict__ er1,
                         const float* __restrict__ ee1,
                         const float* __restrict__ feat1, const float* __restrict__ rproj1,
                         float* out) {
    int g = blockIdx.x;               // 0..63
    int t = threadIdx.x;              // 0..127
    int h = t >> 4;
    int lo = rp2[g], hi = rp2[g + 1];
    float er_g = er1[g * HH + h];     // CLS node g has slot1 == g
    float acc = 0.f, sumex = 0.f;
    for (int i = lo; i < hi; i++) {
        int e = csr2[i];
        int ks = slot1[src[e]];
        int rid = rel_ids[e];
        float sc = el1[ks * HH + h] + er_g + ee1[rid * HH + h];
        sc = sc >= 0.f ? sc : 0.2f * sc;
        float ex = __expf(sc);
        sumex += ex;
        acc += ex * (feat1[ks * HIDD + t] + rproj1[rid * HIDD + t]);
    }
    out[g * HIDD + t] = (hi > lo) ? acc / sumex : 0.f;
}

extern "C" void kernel_launch(void* const* d_in, const int* in_sizes, int n_in,
                              void* d_out, int out_size, void* d_ws, size_t ws_size,
                              hipStream_t stream) {
    const float* ent_table = (const float*)d_in[0];
    const float* rel_table = (const float*)d_in[1];
    const float* W_ent     = (const float*)d_in[2];   // [2,128,128]
    const float* W_rel     = (const float*)d_in[3];   // [2,128,128]
    const float* attn_l    = (const float*)d_in[4];   // [2,8,16]
    const float* attn_r    = (const float*)d_in[5];
    const float* attn_e    = (const float*)d_in[6];
    const int*   ent_ids   = (const int*)d_in[7];
    const int*   rel_ids   = (const int*)d_in[8];
    const int*   src       = (const int*)d_in[9];
    const int*   dst       = (const int*)d_in[10];
    const int*   goffs     = (const int*)d_in[11];
    float*       out       = (float*)d_out;

    char* p = (char*)d_ws;
    auto alloc = [&](size_t nbytes) {
        void* q = (void*)p;
        p += (nbytes + 255) & ~(size_t)255;
        return q;
    };
    float* rproj   = (float*)alloc((size_t)2 * NR * HIDD * 4);
    float* ee      = (float*)alloc((size_t)2 * NR * HH * 4);
    int*   slot2   = (int*)alloc((size_t)NN * 4);
    int*   slot1   = (int*)alloc((size_t)NN * 4);
    int*   slot0   = (int*)alloc((size_t)NN * 4);
    int*   nodesS1 = (int*)alloc((size_t)MAXS1 * 4);
    int*   nodesS0 = (int*)alloc((size_t)MAXS0 * 4);
    int*   e2list  = (int*)alloc((size_t)MAXE2 * 4);
    int*   e1list  = (int*)alloc((size_t)MAXE1 * 4);
    int*   counters= (int*)alloc(8 * 4);
    int*   eseg2   = (int*)alloc((size_t)GRIDS * PER * 4);
    int*   nseg2   = (int*)alloc((size_t)GRIDS * PER * 4);
    int*   eseg1   = (int*)alloc((size_t)GRIDS * PER * 4);
    int*   nseg1   = (int*)alloc((size_t)GRIDS * PER * 4);
    int*   ecnt2   = (int*)alloc((size_t)GRIDS * 4);
    int*   ncnt2   = (int*)alloc((size_t)GRIDS * 4);
    int*   ecnt1   = (int*)alloc((size_t)GRIDS * 4);
    int*   ncnt1   = (int*)alloc((size_t)GRIDS * 4);
    int*   ebase2  = (int*)alloc((size_t)GRIDS * 4);
    int*   nbase2  = (int*)alloc((size_t)GRIDS * 4);
    int*   ebase1  = (int*)alloc((size_t)GRIDS * 4);
    int*   nbase1  = (int*)alloc((size_t)GRIDS * 4);
    int*   deg2    = (int*)alloc((size_t)BB * 4);
    int*   rp2     = (int*)alloc((size_t)(BB + 1) * 4);
    int*   cur2    = (int*)alloc((size_t)BB * 4);
    int*   deg1    = (int*)alloc((size_t)MAXS1 * 4);
    int*   rp1     = (int*)alloc((size_t)(MAXS1 + 1) * 4);
    int*   cur1    = (int*)alloc((size_t)MAXS1 * 4);
    int*   csr2    = (int*)alloc((size_t)MAXE2 * 4);
    int*   csr1    = (int*)alloc((size_t)MAXE1 * 4);
    float* feat0   = (float*)alloc((size_t)MAXS0 * HIDD * 4);
    float* el0     = (float*)alloc((size_t)MAXS0 * HH * 4);
    float* er0     = (float*)alloc((size_t)MAXS0 * HH * 4);
    float* feat1   = (float*)alloc((size_t)MAXS1 * HIDD * 4);
    float* el1     = (float*)alloc((size_t)MAXS1 * HH * 4);
    float* er1     = (float*)alloc((size_t)MAXS1 * HH * 4);

    const float* rproj0 = rproj;
    const float* rproj1 = rproj + (size_t)NR * HIDD;
    const float* ee0 = ee;
    const float* ee1 = ee + (size_t)NR * HH;
    const float* W_ent0 = W_ent;
    const float* W_ent1 = W_ent + HIDD * HIDD;
    const float* attn_l0 = attn_l, *attn_l1 = attn_l + HH * DD;
    const float* attn_r0 = attn_r, *attn_r1 = attn_r + HH * DD;

    hipLaunchKernelGGL(k_init, dim3(256), dim3(256), 0, stream,
                       slot2, slot1, slot0, counters);
    hipLaunchKernelGGL(k_seed, dim3(1), dim3(64), 0, stream,
                       goffs, slot2, slot1, nodesS1);
    hipLaunchKernelGGL(k_scan, dim3(GRIDS), dim3(256), 0, stream,
                       src, dst, slot2, slot1, eseg2, ecnt2, nseg2, ncnt2);
    hipLaunchKernelGGL(k_prefix2, dim3(1), dim3(256), 0, stream,
                       ecnt2, ncnt2, ebase2, nbase2, counters,
                       nodesS1, slot1, slot0, nodesS0);
    hipLaunchKernelGGL(k_compact2, dim3(GRIDS), dim3(256), 0, stream,
                       eseg2, ecnt2, ebase2, nseg2, ncnt2, nbase2,
                       e2list, nodesS1, slot1, slot0, nodesS0, deg2);
    hipLaunchKernelGGL(k_scan, dim3(GRIDS), dim3(256), 0, stream,
                       src, dst, slot1, slot0, eseg1, ecnt1, nseg1, ncnt1);
    hipLaunchKernelGGL(k_prefix1, dim3(1), dim3(256), 0, stream,
                       ecnt1, ncnt1, ebase1, nbase1, counters);
    hipLaunchKernelGGL(k_compact1, dim3(GRIDS), dim3(256), 0, stream,
                       eseg1, ecnt1, ebase1, nseg1, ncnt1, nbase1,
                       e1list, slot0, nodesS0, deg1, counters);
    hipLaunchKernelGGL(k_hist, dim3(256), dim3(256), 0, stream,
                       e2list, e1list, counters, dst, slot2, slot1, deg2, deg1);
    hipLaunchKernelGGL(k_rowptr, dim3(1), dim3(256), 0, stream,
                       deg2, deg1, counters, rp2, rp1, cur2, cur1);
    hipLaunchKernelGGL(k_scatter, dim3(256), dim3(256), 0, stream,
                       e2list, e1list, counters, dst, slot2, slot1,
                       cur2, cur1, csr2, csr1);
    hipLaunchKernelGGL(k_relfeat0, dim3(2 * NR + 1024), dim3(HIDD), 0, stream,
                       rel_table, W_rel, attn_e, rproj, ee,
                       nodesS0, counters, ent_ids, ent_table, W_ent0,
                       attn_l0, attn_r0, feat0, el0, er0);
    hipLaunchKernelGGL(k_layer1, dim3(2048), dim3(HIDD), 0, stream,
                       counters, rp1, csr1, src, rel_ids, slot0,
                       el0, er0, ee0, feat0, rproj0, W_ent1,
                       attn_l1, attn_r1, feat1, el1, er1);
    hipLaunchKernelGGL(k_layer2, dim3(BB), dim3(HIDD), 0, stream,
                       rp2, csr2, src, rel_ids, slot1,
                       el1, er1, ee1, feat1, rproj1, out);
}